// Round 12
// baseline (3938.951 us; speedup 1.0000x reference)
//
#include <hip/hip_runtime.h>
#include <hip/hip_bf16.h>

#define LEAKY_SLOPE 0.2f

typedef short short8 __attribute__((ext_vector_type(8)));
typedef float f32x4 __attribute__((ext_vector_type(4)));

static inline int cdiv(int a, int b) { return (a + b - 1) / b; }

// ---- bf16 split helpers (RNE) ----------------------------------------------
__device__ __forceinline__ float bf2f(unsigned short s) {
    return __uint_as_float(((unsigned int)s) << 16);
}
__device__ __forceinline__ unsigned short f2bf(float x) {
    unsigned int u = __float_as_uint(x);
    return (unsigned short)((u + 0x7FFFu + ((u >> 16) & 1u)) >> 16);
}
__device__ __forceinline__ unsigned short bf_hi(float x, float& rem) {
    unsigned int u = __float_as_uint(x);
    unsigned int hi = (u + 0x7FFFu + ((u >> 16) & 1u)) & 0xFFFF0000u;
    rem = x - __uint_as_float(hi);
    return (unsigned short)(hi >> 16);
}
// Packed row-major split layout for N x 128 matrices (u16 units):
//   hi(r,k) at r*256 + (k>>3)*16 + (k&7);  lo at +8.  One row = 512B contiguous.
//   Quarter q (feats 32q..32q+31) = 128B contiguous at r*256 + q*64.

struct EdgeArgs {
    const int* adj[12];
    int E[12];
    int colOff[12];
};
struct ColPtrs { const int* c[12]; };
struct MutColPtrs { int* c[12]; };

// ---------------------------------------------------------------------------
// Label representation: char-CNN + relu + max over positions.
// ---------------------------------------------------------------------------
__global__ __launch_bounds__(64) void label_kernel(
    const int* __restrict__ labels, const float* __restrict__ char_embed,
    const float* __restrict__ conv_w, const float* __restrict__ conv_b,
    float* __restrict__ lr, int U)
{
    __shared__ float ch[20][16];
    __shared__ int lab[16];
    const int u = blockIdx.x, t = threadIdx.x;
    {
        const int r = t >> 4, i = t & 15;
        const int padrow[4] = {0, 1, 18, 19};
        ch[padrow[r]][i] = 0.f;
    }
    if (t < 16) lab[t] = labels[(size_t)u * 16 + t];
    float cwr[5][16];
    #pragma unroll
    for (int k = 0; k < 5; ++k)
        #pragma unroll
        for (int i = 0; i < 16; ++i)
            cwr[k][i] = conv_w[(k * 16 + i) * 64 + t];
    __syncthreads();
    for (int j = t; j < 256; j += 64)
        ch[2 + (j >> 4)][j & 15] = char_embed[(size_t)lab[j >> 4] * 16 + (j & 15)];
    __syncthreads();
    float aw[16];
    const float b = conv_b[t];
    #pragma unroll
    for (int w = 0; w < 16; ++w) aw[w] = b;
    #pragma unroll
    for (int x = 0; x < 20; ++x)
        #pragma unroll
        for (int i = 0; i < 16; ++i) {
            const float chv = ch[x][i];
            #pragma unroll
            for (int k = 0; k < 5; ++k) {
                const int w = x - k;
                if (w >= 0 && w < 16) aw[w] += chv * cwr[k][i];
            }
        }
    float m = 0.f;
    #pragma unroll
    for (int w = 0; w < 16; ++w) m = fmaxf(m, aw[w]);
    lr[(size_t)u * 64 + t] = m;
}

// ---------------------------------------------------------------------------
// h init -> packed row-major split. Pads zeroed.
// ---------------------------------------------------------------------------
__global__ void init_hP(const int* __restrict__ idx, const float* __restrict__ lr,
                        unsigned short* __restrict__ hP, int N, int NP)
{
    const int i = blockIdx.x * blockDim.x + threadIdx.x;
    if (i >= NP * 16) return;
    const int n = i >> 4, kg = i & 15;
    short8 hi, lo;
    #pragma unroll
    for (int j = 0; j < 8; ++j) { hi[j] = 0; lo[j] = 0; }
    if (n < N && kg < 8) {
        const int id = idx[n];
        #pragma unroll
        for (int j = 0; j < 8; ++j) {
            const float v = lr[(size_t)id * 64 + kg * 8 + j];
            float r; hi[j] = (short)bf_hi(v, r); lo[j] = (short)f2bf(r);
        }
    }
    *(short8*)(hP + (size_t)n * 256 + kg * 16) = hi;
    *(short8*)(hP + (size_t)n * 256 + kg * 16 + 8) = lo;
}

// ---------------------------------------------------------------------------
// CSR build
// ---------------------------------------------------------------------------
__global__ void hist_kernel(EdgeArgs ea, int* __restrict__ deg, int N)
{
    const int t = blockIdx.y;
    const int e = blockIdx.x * blockDim.x + threadIdx.x;
    if (e >= ea.E[t]) return;
    atomicAdd(&deg[(size_t)t * N + ea.adj[t][2 * e + 1]], 1);
}

__global__ __launch_bounds__(256) void scan_a(const int* __restrict__ deg,
                                              int* __restrict__ partial, int N, int nchunk)
{
    const int t = blockIdx.y, b = blockIdx.x;
    const int base = b * 2048;
    int s = 0;
    for (int i = threadIdx.x; i < 2048; i += 256) {
        const int g = base + i;
        if (g < N) s += deg[(size_t)t * N + g];
    }
    __shared__ int sm[256];
    sm[threadIdx.x] = s; __syncthreads();
    for (int off = 128; off > 0; off >>= 1) {
        if (threadIdx.x < off) sm[threadIdx.x] += sm[threadIdx.x + off];
        __syncthreads();
    }
    if (threadIdx.x == 0) partial[t * nchunk + b] = sm[0];
}

__global__ void scan_b(int* __restrict__ partial, int nchunk)
{
    const int t = threadIdx.x;
    if (t >= 12) return;
    int off = 0;
    for (int i = 0; i < nchunk; ++i) {
        const int s = partial[t * nchunk + i];
        partial[t * nchunk + i] = off;
        off += s;
    }
}

__global__ __launch_bounds__(256) void scan_c(const int* __restrict__ deg,
                                              const int* __restrict__ partial,
                                              int* __restrict__ rowptr, int N, int nchunk)
{
    const int t = blockIdx.y, b = blockIdx.x;
    int* rp = rowptr + (size_t)t * (N + 1);
    const int base = b * 2048;
    int v[8]; int s = 0;
    #pragma unroll
    for (int j = 0; j < 8; ++j) {
        const int g = base + threadIdx.x * 8 + j;
        v[j] = (g < N) ? deg[(size_t)t * N + g] : 0;
        s += v[j];
    }
    __shared__ int ts[256];
    ts[threadIdx.x] = s; __syncthreads();
    for (int off = 1; off < 256; off <<= 1) {
        const int val = (threadIdx.x >= off) ? ts[threadIdx.x - off] : 0;
        __syncthreads();
        ts[threadIdx.x] += val;
        __syncthreads();
    }
    int run = partial[t * nchunk + b] + (threadIdx.x ? ts[threadIdx.x - 1] : 0);
    #pragma unroll
    for (int j = 0; j < 8; ++j) {
        const int g = base + threadIdx.x * 8 + j;
        run += v[j];
        if (g < N) rp[g + 1] = run;
    }
    if (b == 0 && threadIdx.x == 0) rp[0] = 0;
}

__global__ void fill_kernel(EdgeArgs ea, const int* __restrict__ rowptr,
                            int* __restrict__ cursor, int* __restrict__ col, int N)
{
    const int t = blockIdx.y;
    const int e = blockIdx.x * blockDim.x + threadIdx.x;
    if (e >= ea.E[t]) return;
    const int s  = ea.adj[t][2 * e];
    const int tg = ea.adj[t][2 * e + 1];
    const int pos = rowptr[(size_t)t * (N + 1) + tg] + atomicAdd(&cursor[(size_t)t * N + tg], 1);
    col[ea.colOff[t] + pos] = s;
}

// ---------------------------------------------------------------------------
// Canonicalize CSR: sort each row's col segment ascending (atomic fill order
// is schedule-dependent; fp32 sum order must be input-determined for the
// harness's cross-call revalidation). Avg degree ~1, max ~12.
// ---------------------------------------------------------------------------
__global__ __launch_bounds__(256) void sort_cols_kernel(
    const int* __restrict__ rowptr, MutColPtrs mc, int N)
{
    const int t = blockIdx.y;
    const int r = blockIdx.x * blockDim.x + threadIdx.x;
    if (r >= N) return;
    int* c = mc.c[t];
    const int s = rowptr[(size_t)t * (N + 1) + r];
    const int e = rowptr[(size_t)t * (N + 1) + r + 1];
    for (int i = s + 1; i < e; ++i) {
        const int key = c[i];
        int j = i - 1;
        while (j >= s && c[j] > key) { c[j + 1] = c[j]; --j; }
        c[j + 1] = key;
    }
}

// ---------------------------------------------------------------------------
// Weight pre-split into fragment-tiled hi/lo bf16.
//   wb[m*32768 + (k>>3)*1024 + c*8 + (k&7)] = hi, +16384 = lo
// ---------------------------------------------------------------------------
struct WSrc { const float* wmsg; const float* gk; const float* grk; const float* w1; };

__global__ void split_w_kernel(WSrc s, unsigned short* __restrict__ wb, int nmat)
{
    const int gidx = blockIdx.x * 256 + threadIdx.x;
    const int m = gidx >> 14, e = gidx & 16383;
    if (m >= nmat) return;
    const int kg = e >> 10, rem = e & 1023, c = rem >> 3, j = rem & 7;
    const int k = kg * 8 + j;
    float x;
    if (m < 72) x = s.wmsg[(size_t)m * 16384 + (size_t)k * 128 + c];
    else if (m < 108) {
        const int g = m - 72, layer = g / 6, r2 = g % 6;
        const float* base = (r2 < 3) ? s.gk : s.grk;
        const int slice = r2 % 3;
        x = base[(size_t)layer * 49152 + (size_t)k * 384 + slice * 128 + c];
    } else x = s.w1[(size_t)k * 128 + c];
    float r; const unsigned short hi = bf_hi(x, r);
    wb[(size_t)m * 32768 + e] = hi;
    wb[(size_t)m * 32768 + 16384 + e] = f2bf(r);
}

// ---------------------------------------------------------------------------
// agg = sum_t ( gather_t(h) @ W_t ), one dispatch/layer. 512 THREADS:
// single-pass gather (128 rows x 4 threads concurrently, no half loop) and
// 16 waves/CU (2 blocks x 8 waves) for 2x latency hiding vs r9's 256-thread
// version. Per etype: register gather (each edge's 512B row read once,
// coalesced, ga[32] f32, no atomics) -> split once at write into swizzled
// LDS panel -> 8-wave MFMA (each wave owns a 64x32 output tile).
// ---------------------------------------------------------------------------
__global__ __launch_bounds__(512) void agg_kernel(
    const unsigned short* __restrict__ hP,
    const int* __restrict__ rowptr, ColPtrs cps,
    const unsigned short* __restrict__ wbL,
    float* __restrict__ agg, int N)
{
    __shared__ unsigned short Sf[32768];   // 16 kg-planes hi + lo at +16384 (64KB)
    const int tid = threadIdx.x, p = blockIdx.x;
    const int R0 = p * 128;
    const int wave = tid >> 6, lane = tid & 63;
    const int wr = wave >> 2, wc = wave & 3, lrow = lane & 15, lkg = lane >> 4;
    const int row = tid >> 2;              // 0..127 (all rows in one pass)
    const int j4 = tid & 3;                // feat quarter owned (32 feats, 128B)
    const int R = R0 + row;
    f32x4 acc[4][2] = {};

    for (int t = 0; t < 12; ++t) {
        const int* __restrict__ rp_t = rowptr + (size_t)t * (N + 1);
        const int* __restrict__ cl = cps.c[t];
        float ga[32];
        #pragma unroll
        for (int j = 0; j < 32; ++j) ga[j] = 0.f;
        if (R < N) {
            const int e1 = rp_t[R + 1];
            for (int e = rp_t[R]; e < e1; ++e) {
                const unsigned short* hp = hP + (size_t)cl[e] * 256 + j4 * 64;
                #pragma unroll
                for (int c = 0; c < 4; ++c) {
                    const short8 hh = *(const short8*)(hp + c * 16);
                    const short8 hl = *(const short8*)(hp + c * 16 + 8);
                    #pragma unroll
                    for (int q = 0; q < 8; ++q)
                        ga[c * 8 + q] += bf2f((unsigned short)hh[q])
                                       + bf2f((unsigned short)hl[q]);
                }
            }
        }
        #pragma unroll
        for (int c = 0; c < 4; ++c) {
            const int kg = j4 * 4 + c;
            short8 hi, lo;
            #pragma unroll
            for (int q = 0; q < 8; ++q) {
                float rem;
                hi[q] = (short)bf_hi(ga[c * 8 + q], rem);
                lo[q] = (short)f2bf(rem);
            }
            const int u = ((kg << 10) + row * 8) ^ (kg << 3);
            *(short8*)(Sf + u) = hi;
            *(short8*)(Sf + u + 16384) = lo;
        }
        __syncthreads();
        {
            const unsigned short* __restrict__ B = wbL + (size_t)t * 32768;
            #pragma unroll
            for (int q = 0; q < 4; ++q) {
                const int kg = q * 4 + lkg;
                short8 ah[4], al[4];
                #pragma unroll
                for (int m = 0; m < 4; ++m) {
                    const int u = ((kg << 10) + (wr * 64 + m * 16 + lrow) * 8) ^ (kg << 3);
                    ah[m] = *(const short8*)(Sf + u);
                    al[m] = *(const short8*)(Sf + u + 16384);
                }
                #pragma unroll
                for (int n = 0; n < 2; ++n) {
                    const int ub = kg * 1024 + (wc * 32 + n * 16 + lrow) * 8;
                    const short8 bh = *(const short8*)(B + ub);
                    const short8 bl = *(const short8*)(B + ub + 16384);
                    #pragma unroll
                    for (int m = 0; m < 4; ++m) {
                        acc[m][n] = __builtin_amdgcn_mfma_f32_16x16x32_bf16(ah[m], bh, acc[m][n], 0, 0, 0);
                        acc[m][n] = __builtin_amdgcn_mfma_f32_16x16x32_bf16(ah[m], bl, acc[m][n], 0, 0, 0);
                        acc[m][n] = __builtin_amdgcn_mfma_f32_16x16x32_bf16(al[m], bh, acc[m][n], 0, 0, 0);
                    }
                }
            }
        }
        __syncthreads();
    }

    #pragma unroll
    for (int m = 0; m < 4; ++m)
        #pragma unroll
        for (int n = 0; n < 2; ++n) {
            const int col = wc * 32 + n * 16 + lrow;
            #pragma unroll
            for (int i = 0; i < 4; ++i) {
                const size_t Rg = (size_t)p * 128 + wr * 64 + m * 16 + lkg * 4 + i;
                agg[Rg * 128 + col] = acc[m][n][i];
            }
        }
}

// ---------------------------------------------------------------------------
// ZR kernel: acc0 = agg@k0 + h@rk0, acc1 = agg@k1 + h@rk1 (8 quarter-stages,
// agg staged from f32 with inline split; h staged from packed). Epilogue:
// Z = sigmoid(acc0+bz) -> f32;  rh = sigmoid(acc1+br)*h -> packed split.
// ---------------------------------------------------------------------------
__global__ __launch_bounds__(256) void zr2_kernel(
    const float* __restrict__ aggf, const unsigned short* __restrict__ hP,
    const unsigned short* __restrict__ k0, const unsigned short* __restrict__ k1,
    const unsigned short* __restrict__ rk0, const unsigned short* __restrict__ rk1,
    const float* __restrict__ bias,
    float* __restrict__ Zf, unsigned short* __restrict__ rhP)
{
    __shared__ unsigned short lds[2][8192];
    const int tid = threadIdx.x, p = blockIdx.x;
    const int wave = tid >> 6, lane = tid & 63;
    const int wr = wave >> 1, wc = wave & 1, lrow = lane & 15, lkg = lane >> 4;
    f32x4 acc[2][4][4] = {};
    float fv[16];
    short8 ph[2], pl[2];

    auto ldq = [&](int s) {
        const int q = s & 3;
        #pragma unroll
        for (int j = 0; j < 2; ++j) {
            const int cid = j * 256 + tid, kgl = cid >> 7, row = cid & 127;
            if (s < 4) {
                const float* a = aggf + ((size_t)p * 128 + row) * 128 + q * 32 + kgl * 8;
                const float4 v0 = *(const float4*)(a);
                const float4 v1 = *(const float4*)(a + 4);
                fv[j*8+0]=v0.x; fv[j*8+1]=v0.y; fv[j*8+2]=v0.z; fv[j*8+3]=v0.w;
                fv[j*8+4]=v1.x; fv[j*8+5]=v1.y; fv[j*8+6]=v1.z; fv[j*8+7]=v1.w;
            } else {
                const unsigned short* hp = hP + ((size_t)p * 128 + row) * 256 + (q * 4 + kgl) * 16;
                ph[j] = *(const short8*)(hp);
                pl[j] = *(const short8*)(hp + 8);
            }
        }
    };
    auto stq = [&](int buf, int s) {
        unsigned short* L = lds[buf];
        #pragma unroll
        for (int j = 0; j < 2; ++j) {
            const int cid = j * 256 + tid, kgl = cid >> 7, row = cid & 127;
            const int u = (kgl * 1024 + row * 8) ^ (kgl << 3);
            short8 hi, lo;
            if (s < 4) {
                #pragma unroll
                for (int q8 = 0; q8 < 8; ++q8) {
                    float rem; hi[q8] = (short)bf_hi(fv[j*8+q8], rem); lo[q8] = (short)f2bf(rem);
                }
            } else { hi = ph[j]; lo = pl[j]; }
            *(short8*)(L + u) = hi;
            *(short8*)(L + u + 4096) = lo;
        }
    };
    auto mfma_q = [&](int buf, int s) {
        const unsigned short* L = lds[buf];
        const int q = s & 3;
        short8 ah[4], al[4];
        #pragma unroll
        for (int m = 0; m < 4; ++m) {
            const int u = ((lkg << 10) + (wr * 64 + m * 16 + lrow) * 8) ^ (lkg << 3);
            ah[m] = *(const short8*)(L + u);
            al[m] = *(const short8*)(L + u + 4096);
        }
        const unsigned short* Bt[2] = { (s < 4) ? k0 : rk0, (s < 4) ? k1 : rk1 };
        #pragma unroll
        for (int t = 0; t < 2; ++t) {
            const unsigned short* __restrict__ B = Bt[t];
            #pragma unroll
            for (int n = 0; n < 4; ++n) {
                const int ub = (q * 4 + lkg) * 1024 + (wc * 64 + n * 16 + lrow) * 8;
                const short8 bh = *(const short8*)(B + ub);
                const short8 bl = *(const short8*)(B + ub + 16384);
                #pragma unroll
                for (int m = 0; m < 4; ++m) {
                    acc[t][m][n] = __builtin_amdgcn_mfma_f32_16x16x32_bf16(ah[m], bh, acc[t][m][n], 0, 0, 0);
                    acc[t][m][n] = __builtin_amdgcn_mfma_f32_16x16x32_bf16(ah[m], bl, acc[t][m][n], 0, 0, 0);
                    acc[t][m][n] = __builtin_amdgcn_mfma_f32_16x16x32_bf16(al[m], bh, acc[t][m][n], 0, 0, 0);
                }
            }
        }
    };

    ldq(0); stq(0, 0); ldq(1);
    __syncthreads();
    #pragma unroll
    for (int s = 0; s < 8; ++s) {
        mfma_q(s & 1, s);
        if (s < 7) {
            stq((s + 1) & 1, s + 1);
            if (s < 6) ldq(s + 2);
            __syncthreads();
        }
    }

    #pragma unroll
    for (int m = 0; m < 4; ++m)
        #pragma unroll
        for (int n = 0; n < 4; ++n) {
            const int col = wc * 64 + n * 16 + lrow;
            #pragma unroll
            for (int i = 0; i < 4; ++i) {
                const int rl = wr * 64 + m * 16 + lkg * 4 + i;
                const size_t R = (size_t)p * 128 + rl;
                const float z = 1.f / (1.f + __expf(-(acc[0][m][n][i] + bias[col])));
                Zf[R * 128 + col] = z;
                const float r = 1.f / (1.f + __expf(-(acc[1][m][n][i] + bias[128 + col])));
                const size_t hu = R * 256 + (size_t)(col >> 3) * 16 + (col & 7);
                const float h = bf2f(hP[hu]) + bf2f(hP[hu + 8]);
                float rem; const unsigned short hh = bf_hi(r * h, rem);
                rhP[hu] = hh;
                rhP[hu + 8] = f2bf(rem);
            }
        }
}

// ---------------------------------------------------------------------------
// G kernel + fused GRU update: G = agg@k2 + rh@rk2 + bg;
// h' = Z*h + (1-Z)*tanh(G), written packed in place (own panel only).
// ---------------------------------------------------------------------------
__global__ __launch_bounds__(256) void g2_kernel(
    const float* __restrict__ aggf, const unsigned short* __restrict__ rhP,
    const unsigned short* __restrict__ k2, const unsigned short* __restrict__ rk2,
    const float* __restrict__ bias, const float* __restrict__ Zf,
    unsigned short* __restrict__ hP)
{
    __shared__ unsigned short lds[2][8192];
    const int tid = threadIdx.x, p = blockIdx.x;
    const int wave = tid >> 6, lane = tid & 63;
    const int wr = wave >> 1, wc = wave & 1, lrow = lane & 15, lkg = lane >> 4;
    f32x4 acc[4][4] = {};
    float fv[16];
    short8 ph[2], pl[2];

    auto ldq = [&](int s) {
        const int q = s & 3;
        #pragma unroll
        for (int j = 0; j < 2; ++j) {
            const int cid = j * 256 + tid, kgl = cid >> 7, row = cid & 127;
            if (s < 4) {
                const float* a = aggf + ((size_t)p * 128 + row) * 128 + q * 32 + kgl * 8;
                const float4 v0 = *(const float4*)(a);
                const float4 v1 = *(const float4*)(a + 4);
                fv[j*8+0]=v0.x; fv[j*8+1]=v0.y; fv[j*8+2]=v0.z; fv[j*8+3]=v0.w;
                fv[j*8+4]=v1.x; fv[j*8+5]=v1.y; fv[j*8+6]=v1.z; fv[j*8+7]=v1.w;
            } else {
                const unsigned short* hp = rhP + ((size_t)p * 128 + row) * 256 + (q * 4 + kgl) * 16;
                ph[j] = *(const short8*)(hp);
                pl[j] = *(const short8*)(hp + 8);
            }
        }
    };
    auto stq = [&](int buf, int s) {
        unsigned short* L = lds[buf];
        #pragma unroll
        for (int j = 0; j < 2; ++j) {
            const int cid = j * 256 + tid, kgl = cid >> 7, row = cid & 127;
            const int u = (kgl * 1024 + row * 8) ^ (kgl << 3);
            short8 hi, lo;
            if (s < 4) {
                #pragma unroll
                for (int q8 = 0; q8 < 8; ++q8) {
                    float rem; hi[q8] = (short)bf_hi(fv[j*8+q8], rem); lo[q8] = (short)f2bf(rem);
                }
            } else { hi = ph[j]; lo = pl[j]; }
            *(short8*)(L + u) = hi;
            *(short8*)(L + u + 4096) = lo;
        }
    };
    auto mfma_q = [&](int buf, int s) {
        const unsigned short* L = lds[buf];
        const int q = s & 3;
        short8 ah[4], al[4];
        #pragma unroll
        for (int m = 0; m < 4; ++m) {
            const int u = ((lkg << 10) + (wr * 64 + m * 16 + lrow) * 8) ^ (lkg << 3);
            ah[m] = *(const short8*)(L + u);
            al[m] = *(const short8*)(L + u + 4096);
        }
        const unsigned short* __restrict__ B = (s < 4) ? k2 : rk2;
        #pragma unroll
        for (int n = 0; n < 4; ++n) {
            const int ub = (q * 4 + lkg) * 1024 + (wc * 64 + n * 16 + lrow) * 8;
            const short8 bh = *(const short8*)(B + ub);
            const short8 bl = *(const short8*)(B + ub + 16384);
            #pragma unroll
            for (int m = 0; m < 4; ++m) {
                acc[m][n] = __builtin_amdgcn_mfma_f32_16x16x32_bf16(ah[m], bh, acc[m][n], 0, 0, 0);
                acc[m][n] = __builtin_amdgcn_mfma_f32_16x16x32_bf16(ah[m], bl, acc[m][n], 0, 0, 0);
                acc[m][n] = __builtin_amdgcn_mfma_f32_16x16x32_bf16(al[m], bh, acc[m][n], 0, 0, 0);
            }
        }
    };

    ldq(0); stq(0, 0); ldq(1);
    __syncthreads();
    #pragma unroll
    for (int s = 0; s < 8; ++s) {
        mfma_q(s & 1, s);
        if (s < 7) {
            stq((s + 1) & 1, s + 1);
            if (s < 6) ldq(s + 2);
            __syncthreads();
        }
    }

    #pragma unroll
    for (int m = 0; m < 4; ++m)
        #pragma unroll
        for (int n = 0; n < 4; ++n) {
            const int col = wc * 64 + n * 16 + lrow;
            #pragma unroll
            for (int i = 0; i < 4; ++i) {
                const int rl = wr * 64 + m * 16 + lkg * 4 + i;
                const size_t R = (size_t)p * 128 + rl;
                const float g = acc[m][n][i] + bias[col];
                const size_t hu = R * 256 + (size_t)(col >> 3) * 16 + (col & 7);
                const float h = bf2f(hP[hu]) + bf2f(hP[hu + 8]);
                const float z = Zf[R * 128 + col];
                const float hn = z * h + (1.f - z) * tanhf(g);
                float rem; const unsigned short hh = bf_hi(hn, rem);
                hP[hu] = hh;
                hP[hu + 8] = f2bf(rem);
            }
        }
}

// ---------------------------------------------------------------------------
// V1 = leaky(h @ w1 + b1) -> f32
// ---------------------------------------------------------------------------
__global__ __launch_bounds__(256) void v1_kernel(
    const unsigned short* __restrict__ hP, const unsigned short* __restrict__ w1b,
    const float* __restrict__ bias, float* __restrict__ outF)
{
    __shared__ unsigned short lds[2][8192];
    const int tid = threadIdx.x, p = blockIdx.x;
    const int wave = tid >> 6, lane = tid & 63;
    const int wr = wave >> 1, wc = wave & 1, lrow = lane & 15, lkg = lane >> 4;
    f32x4 acc[4][4] = {};
    short8 ph[2], pl[2];

    auto ldq = [&](int s) {
        #pragma unroll
        for (int j = 0; j < 2; ++j) {
            const int cid = j * 256 + tid, kgl = cid >> 7, row = cid & 127;
            const unsigned short* hp = hP + ((size_t)p * 128 + row) * 256 + (s * 4 + kgl) * 16;
            ph[j] = *(const short8*)(hp);
            pl[j] = *(const short8*)(hp + 8);
        }
    };
    auto stq = [&](int buf) {
        unsigned short* L = lds[buf];
        #pragma unroll
        for (int j = 0; j < 2; ++j) {
            const int cid = j * 256 + tid, kgl = cid >> 7, row = cid & 127;
            const int u = (kgl * 1024 + row * 8) ^ (kgl << 3);
            *(short8*)(L + u) = ph[j];
            *(short8*)(L + u + 4096) = pl[j];
        }
    };
    auto mfma_q = [&](int buf, int s) {
        const unsigned short* L = lds[buf];
        short8 ah[4], al[4];
        #pragma unroll
        for (int m = 0; m < 4; ++m) {
            const int u = ((lkg << 10) + (wr * 64 + m * 16 + lrow) * 8) ^ (lkg << 3);
            ah[m] = *(const short8*)(L + u);
            al[m] = *(const short8*)(L + u + 4096);
        }
        #pragma unroll
        for (int n = 0; n < 4; ++n) {
            const int ub = (s * 4 + lkg) * 1024 + (wc * 64 + n * 16 + lrow) * 8;
            const short8 bh = *(const short8*)(w1b + ub);
            const short8 bl = *(const short8*)(w1b + ub + 16384);
            #pragma unroll
            for (int m = 0; m < 4; ++m) {
                acc[m][n] = __builtin_amdgcn_mfma_f32_16x16x32_bf16(ah[m], bh, acc[m][n], 0, 0, 0);
                acc[m][n] = __builtin_amdgcn_mfma_f32_16x16x32_bf16(ah[m], bl, acc[m][n], 0, 0, 0);
                acc[m][n] = __builtin_amdgcn_mfma_f32_16x16x32_bf16(al[m], bh, acc[m][n], 0, 0, 0);
            }
        }
    };

    ldq(0); stq(0); ldq(1);
    __syncthreads();
    #pragma unroll
    for (int s = 0; s < 4; ++s) {
        mfma_q(s & 1, s);
        if (s < 3) {
            stq((s + 1) & 1);
            if (s < 2) ldq(s + 2);
            __syncthreads();
        }
    }

    #pragma unroll
    for (int m = 0; m < 4; ++m)
        #pragma unroll
        for (int n = 0; n < 4; ++n) {
            const int col = wc * 64 + n * 16 + lrow;
            #pragma unroll
            for (int i = 0; i < 4; ++i) {
                const size_t R = (size_t)p * 128 + wr * 64 + m * 16 + lkg * 4 + i;
                float v = acc[m][n][i] + bias[col];
                v = v > 0.f ? v : LEAKY_SLOPE * v;
                outF[R * 128 + col] = v;
            }
        }
}

// ---------------------------------------------------------------------------
// Final: thread-per-node; wave-uniform graph atomic (n2g sorted).
// ---------------------------------------------------------------------------
__global__ __launch_bounds__(256) void final_kernel(
    const unsigned short* __restrict__ hP, const float* __restrict__ V1,
    const int* __restrict__ n2g,
    const float* __restrict__ w2, const float* __restrict__ b2,
    const float* __restrict__ w3, const float* __restrict__ b3,
    const float* __restrict__ w4, const float* __restrict__ b4,
    const float* __restrict__ score_w, const float* __restrict__ score_b,
    float* __restrict__ out, int N)
{
    const int n = blockIdx.x * blockDim.x + threadIdx.x;
    const int nc = n < N ? n : N - 1;
    const int g = n2g[nc];

    float sp = score_b[0];
    #pragma unroll 4
    for (int kg = 0; kg < 16; ++kg) {
        const size_t hu = (size_t)nc * 256 + kg * 16;
        const short8 hh = *(const short8*)(hP + hu);
        const short8 hl = *(const short8*)(hP + hu + 8);
        #pragma unroll
        for (int j = 0; j < 8; ++j)
            sp += (bf2f((unsigned short)hh[j]) + bf2f((unsigned short)hl[j])) * score_w[kg * 8 + j];
    }

    float V2[32];
    #pragma unroll
    for (int j = 0; j < 32; ++j) V2[j] = b2[j];
    #pragma unroll 2
    for (int k = 0; k < 128; k += 4) {
        const float4 v1 = *reinterpret_cast<const float4*>(V1 + (size_t)nc * 128 + k);
        const float vv[4] = {v1.x, v1.y, v1.z, v1.w};
        #pragma unroll
        for (int kk = 0; kk < 4; ++kk)
            #pragma unroll
            for (int j = 0; j < 32; ++j)
                V2[j] += vv[kk] * w2[(k + kk) * 32 + j];
    }
    #pragma unroll
    for (int j = 0; j < 32; ++j) { const float x = V2[j]; V2[j] = x > 0.f ? x : LEAKY_SLOPE * x; }

    float V3[8];
    #pragma unroll
    for (int j = 0; j < 8; ++j) V3[j] = b3[j];
    #pragma unroll
    for (int k = 0; k < 32; ++k)
        #pragma unroll
        for (int j = 0; j < 8; ++j) V3[j] += V2[k] * w3[k * 8 + j];
    #pragma unroll
    for (int j = 0; j < 8; ++j) { const float x = V3[j]; V3[j] = x > 0.f ? x : LEAKY_SLOPE * x; }

    float o4 = b4[0];
    #pragma unroll
    for (int j = 0; j < 8; ++j) o4 += V3[j] * w4[j];

    const float sc = 1.f / (1.f + __expf(-sp));
    float val = (n < N) ? sc * o4 : 0.f;

    const int g0 = __shfl(g, 0, 64);
    if (__all(g == g0)) {
        #pragma unroll
        for (int d = 32; d > 0; d >>= 1) val += __shfl_xor(val, d, 64);
        if ((threadIdx.x & 63) == 0) unsafeAtomicAdd(out + g0, val);
    } else {
        if (n < N) unsafeAtomicAdd(out + g, val);
    }
}

// ---------------------------------------------------------------------------
extern "C" void kernel_launch(void* const* d_in, const int* in_sizes, int n_in,
                              void* d_out, int out_size, void* d_ws, size_t ws_size,
                              hipStream_t stream)
{
    (void)n_in;
    const int* labels   = (const int*)d_in[1];
    const int* nidx     = (const int*)d_in[2];
    const int* n2g      = (const int*)d_in[3];
    EdgeArgs ea;
    int Emax = 0, Etot = 0;
    for (int t = 0; t < 12; ++t) {
        ea.adj[t] = (const int*)d_in[5 + t];
        ea.E[t] = in_sizes[5 + t] / 2;
        ea.colOff[t] = Etot;
        Etot += ea.E[t];
        if (ea.E[t] > Emax) Emax = ea.E[t];
    }
    const float* char_embed = (const float*)d_in[17];
    const float* conv_w     = (const float*)d_in[18];
    const float* conv_b     = (const float*)d_in[19];
    const float* W_msg      = (const float*)d_in[20];
    const float* gru_k      = (const float*)d_in[21];
    const float* gru_rk     = (const float*)d_in[22];
    const float* gru_b      = (const float*)d_in[23];
    const float* score_w    = (const float*)d_in[24];
    const float* score_b    = (const float*)d_in[25];
    const float* w1 = (const float*)d_in[26];
    const float* b1 = (const float*)d_in[27];
    const float* w2 = (const float*)d_in[28];
    const float* b2 = (const float*)d_in[29];
    const float* w3 = (const float*)d_in[30];
    const float* b3 = (const float*)d_in[31];
    const float* w4 = (const float*)d_in[32];
    const float* b4 = (const float*)d_in[33];

    const int N = in_sizes[2];
    const int U = in_sizes[1] / 16;
    const int G = out_size;
    float* out = (float*)d_out;

    const int NPB = cdiv(N, 128);
    const int NP  = NPB * 128;
    const int NCHUNK = cdiv(N, 2048);
    const int NMAT = 109;

    // ---- workspace ----
    float* ws = (float*)d_ws;
    size_t o = 0;
    float* lr   = ws + o; o += (size_t)U * 64;
    float* hPf  = ws + o; o += (size_t)NP * 128;   // h packed-split (u16 hi/lo)
    float* aggf = ws + o; o += (size_t)NP * 128;   // agg f32
    float* Zf   = ws + o; o += (size_t)NP * 128;   // Z f32 (later V1 f32)
    float* rhPf = ws + o; o += (size_t)NP * 128;   // rh packed-split
    float* wbf  = ws + o; o += (size_t)NMAT * 16384;
    int* rowptr = (int*)(ws + o);
    int* colarr = rowptr + (size_t)12 * (N + 1);
    const size_t total_bytes = o * sizeof(float)
        + ((size_t)12 * (N + 1) + (size_t)Etot) * sizeof(int);
    if (total_bytes > ws_size) return;

    unsigned short* hP  = (unsigned short*)hPf;
    unsigned short* rhP = (unsigned short*)rhPf;
    unsigned short* wb  = (unsigned short*)wbf;

    // CSR temporaries inside Zf region (free until layer-0 zr2)
    int* deg     = (int*)Zf;
    int* cursor  = deg + (size_t)12 * N;
    int* partial = cursor + (size_t)12 * N;

    hipMemsetAsync(d_out, 0, (size_t)G * sizeof(float), stream);
    hipMemsetAsync(deg, 0, ((size_t)24 * N + 12 * NCHUNK) * sizeof(int), stream);

    MutColPtrs mcp;
    ColPtrs cps;
    for (int t = 0; t < 12; ++t) {
        mcp.c[t] = colarr + ea.colOff[t];
        cps.c[t] = colarr + ea.colOff[t];
    }

    {
        const dim3 ge(cdiv(Emax, 256), 12);
        const dim3 gs(NCHUNK, 12);
        const dim3 gn(cdiv(N, 256), 12);
        hist_kernel<<<ge, 256, 0, stream>>>(ea, deg, N);
        scan_a<<<gs, 256, 0, stream>>>(deg, partial, N, NCHUNK);
        scan_b<<<1, 64, 0, stream>>>(partial, NCHUNK);
        scan_c<<<gs, 256, 0, stream>>>(deg, partial, rowptr, N, NCHUNK);
        fill_kernel<<<ge, 256, 0, stream>>>(ea, rowptr, cursor, colarr, N);
        // Canonical order: makes every downstream fp32 reduction call-invariant.
        sort_cols_kernel<<<gn, 256, 0, stream>>>(rowptr, mcp, N);
    }

    WSrc wsrc{W_msg, gru_k, gru_rk, w1};
    split_w_kernel<<<cdiv(NMAT * 16384, 256), 256, 0, stream>>>(wsrc, wb, NMAT);
    label_kernel<<<U, 64, 0, stream>>>(labels, char_embed, conv_w, conv_b, lr, U);
    init_hP<<<cdiv(NP * 16, 256), 256, 0, stream>>>(nidx, lr, hP, N, NP);

    auto wbm = [&](int m) { return wb + (size_t)m * 32768; };

    for (int layer = 0; layer < 6; ++layer) {
        const float* bl = gru_b + (size_t)layer * 384;
        const int mk = 72 + layer * 6;
        agg_kernel<<<NPB, 512, 0, stream>>>(hP, rowptr, cps,
                                            wbm(layer * 12), aggf, N);
        zr2_kernel<<<NPB, 256, 0, stream>>>(aggf, hP, wbm(mk + 0), wbm(mk + 1),
                                            wbm(mk + 3), wbm(mk + 4), bl, Zf, rhP);
        g2_kernel<<<NPB, 256, 0, stream>>>(aggf, rhP, wbm(mk + 2), wbm(mk + 5),
                                           bl + 256, Zf, hP);
    }
    v1_kernel<<<NPB, 256, 0, stream>>>(hP, wbm(108), b1, Zf);
    final_kernel<<<cdiv(N, 256), 256, 0, stream>>>(hP, Zf, n2g, w2, b2, w3, b3, w4, b4,
                                                   score_w, score_b, out, N);
}

// Round 13
// 3646.394 us; speedup vs baseline: 1.0802x; 1.0802x over previous
//
#include <hip/hip_runtime.h>
#include <hip/hip_bf16.h>

#define LEAKY_SLOPE 0.2f

typedef short short8 __attribute__((ext_vector_type(8)));
typedef float f32x4 __attribute__((ext_vector_type(4)));

static inline int cdiv(int a, int b) { return (a + b - 1) / b; }

// ---- bf16 split helpers (RNE) ----------------------------------------------
__device__ __forceinline__ float bf2f(unsigned short s) {
    return __uint_as_float(((unsigned int)s) << 16);
}
__device__ __forceinline__ unsigned short f2bf(float x) {
    unsigned int u = __float_as_uint(x);
    return (unsigned short)((u + 0x7FFFu + ((u >> 16) & 1u)) >> 16);
}
__device__ __forceinline__ unsigned short bf_hi(float x, float& rem) {
    unsigned int u = __float_as_uint(x);
    unsigned int hi = (u + 0x7FFFu + ((u >> 16) & 1u)) & 0xFFFF0000u;
    rem = x - __uint_as_float(hi);
    return (unsigned short)(hi >> 16);
}
// Packed row-major split layout for N x 128 matrices (u16 units):
//   hi(r,k) at r*256 + (k>>3)*16 + (k&7);  lo at +8.  One row = 512B contiguous.

struct EdgeArgs {
    const int* adj[12];
    int E[12];
    int colOff[12];
};
struct ColPtrs { const int* c[12]; };
struct MutColPtrs { int* c[12]; };

// ---------------------------------------------------------------------------
// Label representation: char-CNN + relu + max over positions.
// ---------------------------------------------------------------------------
__global__ __launch_bounds__(64) void label_kernel(
    const int* __restrict__ labels, const float* __restrict__ char_embed,
    const float* __restrict__ conv_w, const float* __restrict__ conv_b,
    float* __restrict__ lr, int U)
{
    __shared__ float ch[20][16];
    __shared__ int lab[16];
    const int u = blockIdx.x, t = threadIdx.x;
    {
        const int r = t >> 4, i = t & 15;
        const int padrow[4] = {0, 1, 18, 19};
        ch[padrow[r]][i] = 0.f;
    }
    if (t < 16) lab[t] = labels[(size_t)u * 16 + t];
    float cwr[5][16];
    #pragma unroll
    for (int k = 0; k < 5; ++k)
        #pragma unroll
        for (int i = 0; i < 16; ++i)
            cwr[k][i] = conv_w[(k * 16 + i) * 64 + t];
    __syncthreads();
    for (int j = t; j < 256; j += 64)
        ch[2 + (j >> 4)][j & 15] = char_embed[(size_t)lab[j >> 4] * 16 + (j & 15)];
    __syncthreads();
    float aw[16];
    const float b = conv_b[t];
    #pragma unroll
    for (int w = 0; w < 16; ++w) aw[w] = b;
    #pragma unroll
    for (int x = 0; x < 20; ++x)
        #pragma unroll
        for (int i = 0; i < 16; ++i) {
            const float chv = ch[x][i];
            #pragma unroll
            for (int k = 0; k < 5; ++k) {
                const int w = x - k;
                if (w >= 0 && w < 16) aw[w] += chv * cwr[k][i];
            }
        }
    float m = 0.f;
    #pragma unroll
    for (int w = 0; w < 16; ++w) m = fmaxf(m, aw[w]);
    lr[(size_t)u * 64 + t] = m;
}

// ---------------------------------------------------------------------------
// h init -> packed row-major split. Pads zeroed.
// ---------------------------------------------------------------------------
__global__ void init_hP(const int* __restrict__ idx, const float* __restrict__ lr,
                        unsigned short* __restrict__ hP, int N, int NP)
{
    const int i = blockIdx.x * blockDim.x + threadIdx.x;
    if (i >= NP * 16) return;
    const int n = i >> 4, kg = i & 15;
    short8 hi, lo;
    #pragma unroll
    for (int j = 0; j < 8; ++j) { hi[j] = 0; lo[j] = 0; }
    if (n < N && kg < 8) {
        const int id = idx[n];
        #pragma unroll
        for (int j = 0; j < 8; ++j) {
            const float v = lr[(size_t)id * 64 + kg * 8 + j];
            float r; hi[j] = (short)bf_hi(v, r); lo[j] = (short)f2bf(r);
        }
    }
    *(short8*)(hP + (size_t)n * 256 + kg * 16) = hi;
    *(short8*)(hP + (size_t)n * 256 + kg * 16 + 8) = lo;
}

// ---------------------------------------------------------------------------
// CSR build
// ---------------------------------------------------------------------------
__global__ void hist_kernel(EdgeArgs ea, int* __restrict__ deg, int N)
{
    const int t = blockIdx.y;
    const int e = blockIdx.x * blockDim.x + threadIdx.x;
    if (e >= ea.E[t]) return;
    atomicAdd(&deg[(size_t)t * N + ea.adj[t][2 * e + 1]], 1);
}

__global__ __launch_bounds__(256) void scan_a(const int* __restrict__ deg,
                                              int* __restrict__ partial, int N, int nchunk)
{
    const int t = blockIdx.y, b = blockIdx.x;
    const int base = b * 2048;
    int s = 0;
    for (int i = threadIdx.x; i < 2048; i += 256) {
        const int g = base + i;
        if (g < N) s += deg[(size_t)t * N + g];
    }
    __shared__ int sm[256];
    sm[threadIdx.x] = s; __syncthreads();
    for (int off = 128; off > 0; off >>= 1) {
        if (threadIdx.x < off) sm[threadIdx.x] += sm[threadIdx.x + off];
        __syncthreads();
    }
    if (threadIdx.x == 0) partial[t * nchunk + b] = sm[0];
}

__global__ void scan_b(int* __restrict__ partial, int nchunk)
{
    const int t = threadIdx.x;
    if (t >= 12) return;
    int off = 0;
    for (int i = 0; i < nchunk; ++i) {
        const int s = partial[t * nchunk + i];
        partial[t * nchunk + i] = off;
        off += s;
    }
}

__global__ __launch_bounds__(256) void scan_c(const int* __restrict__ deg,
                                              const int* __restrict__ partial,
                                              int* __restrict__ rowptr, int N, int nchunk)
{
    const int t = blockIdx.y, b = blockIdx.x;
    int* rp = rowptr + (size_t)t * (N + 1);
    const int base = b * 2048;
    int v[8]; int s = 0;
    #pragma unroll
    for (int j = 0; j < 8; ++j) {
        const int g = base + threadIdx.x * 8 + j;
        v[j] = (g < N) ? deg[(size_t)t * N + g] : 0;
        s += v[j];
    }
    __shared__ int ts[256];
    ts[threadIdx.x] = s; __syncthreads();
    for (int off = 1; off < 256; off <<= 1) {
        const int val = (threadIdx.x >= off) ? ts[threadIdx.x - off] : 0;
        __syncthreads();
        ts[threadIdx.x] += val;
        __syncthreads();
    }
    int run = partial[t * nchunk + b] + (threadIdx.x ? ts[threadIdx.x - 1] : 0);
    #pragma unroll
    for (int j = 0; j < 8; ++j) {
        const int g = base + threadIdx.x * 8 + j;
        run += v[j];
        if (g < N) rp[g + 1] = run;
    }
    if (b == 0 && threadIdx.x == 0) rp[0] = 0;
}

__global__ void fill_kernel(EdgeArgs ea, const int* __restrict__ rowptr,
                            int* __restrict__ cursor, int* __restrict__ col, int N)
{
    const int t = blockIdx.y;
    const int e = blockIdx.x * blockDim.x + threadIdx.x;
    if (e >= ea.E[t]) return;
    const int s  = ea.adj[t][2 * e];
    const int tg = ea.adj[t][2 * e + 1];
    const int pos = rowptr[(size_t)t * (N + 1) + tg] + atomicAdd(&cursor[(size_t)t * N + tg], 1);
    col[ea.colOff[t] + pos] = s;
}

// ---------------------------------------------------------------------------
// Canonicalize CSR: sort each row's col segment ascending (atomic fill order
// is schedule-dependent; fp32 sum order must be input-determined for the
// harness's cross-call revalidation). Avg degree ~1, max ~12.
// ---------------------------------------------------------------------------
__global__ __launch_bounds__(256) void sort_cols_kernel(
    const int* __restrict__ rowptr, MutColPtrs mc, int N)
{
    const int t = blockIdx.y;
    const int r = blockIdx.x * blockDim.x + threadIdx.x;
    if (r >= N) return;
    int* c = mc.c[t];
    const int s = rowptr[(size_t)t * (N + 1) + r];
    const int e = rowptr[(size_t)t * (N + 1) + r + 1];
    for (int i = s + 1; i < e; ++i) {
        const int key = c[i];
        int j = i - 1;
        while (j >= s && c[j] > key) { c[j + 1] = c[j]; --j; }
        c[j + 1] = key;
    }
}

// ---------------------------------------------------------------------------
// Weight pre-split into fragment-tiled hi/lo bf16.
//   wb[m*32768 + (k>>3)*1024 + c*8 + (k&7)] = hi, +16384 = lo
// ---------------------------------------------------------------------------
struct WSrc { const float* wmsg; const float* gk; const float* grk; const float* w1; };

__global__ void split_w_kernel(WSrc s, unsigned short* __restrict__ wb, int nmat)
{
    const int gidx = blockIdx.x * 256 + threadIdx.x;
    const int m = gidx >> 14, e = gidx & 16383;
    if (m >= nmat) return;
    const int kg = e >> 10, rem = e & 1023, c = rem >> 3, j = rem & 7;
    const int k = kg * 8 + j;
    float x;
    if (m < 72) x = s.wmsg[(size_t)m * 16384 + (size_t)k * 128 + c];
    else if (m < 108) {
        const int g = m - 72, layer = g / 6, r2 = g % 6;
        const float* base = (r2 < 3) ? s.gk : s.grk;
        const int slice = r2 % 3;
        x = base[(size_t)layer * 49152 + (size_t)k * 384 + slice * 128 + c];
    } else x = s.w1[(size_t)k * 128 + c];
    float r; const unsigned short hi = bf_hi(x, r);
    wb[(size_t)m * 32768 + e] = hi;
    wb[(size_t)m * 32768 + 16384 + e] = f2bf(r);
}

// ---------------------------------------------------------------------------
// agg = sum_t ( gather_t(h) @ W_t ), one dispatch/layer.  [r11-proven form]
// Per etype: per-ROW register gather (4 threads/row x 32 feats, two 64-row
// halves; each edge's 512B packed row read once, coalesced; ga[32] f32, no
// atomics) -> split once at write into swizzled LDS panel -> MFMA quarters.
// ---------------------------------------------------------------------------
__global__ __launch_bounds__(256) void agg_kernel(
    const unsigned short* __restrict__ hP,
    const int* __restrict__ rowptr, ColPtrs cps,
    const unsigned short* __restrict__ wbL,
    float* __restrict__ agg, int N)
{
    __shared__ unsigned short Sf[32768];   // 16 kg-planes hi + lo at +16384 (64KB)
    const int tid = threadIdx.x, p = blockIdx.x;
    const int R0 = p * 128;
    const int wave = tid >> 6, lane = tid & 63;
    const int wr = wave >> 1, wc = wave & 1, lrow = lane & 15, lkg = lane >> 4;
    const int rhalf = tid >> 2;            // 0..63
    const int j4 = tid & 3;                // feat quarter owned
    f32x4 acc[4][4] = {};

    for (int t = 0; t < 12; ++t) {
        const int* __restrict__ rp_t = rowptr + (size_t)t * (N + 1);
        const int* __restrict__ cl = cps.c[t];
        #pragma unroll
        for (int half = 0; half < 2; ++half) {
            const int row = half * 64 + rhalf;
            const int R = R0 + row;
            float ga[32];
            #pragma unroll
            for (int j = 0; j < 32; ++j) ga[j] = 0.f;
            if (R < N) {
                const int e1 = rp_t[R + 1];
                for (int e = rp_t[R]; e < e1; ++e) {
                    const unsigned short* hp = hP + (size_t)cl[e] * 256 + j4 * 64;
                    #pragma unroll
                    for (int c = 0; c < 4; ++c) {
                        const short8 hh = *(const short8*)(hp + c * 16);
                        const short8 hl = *(const short8*)(hp + c * 16 + 8);
                        #pragma unroll
                        for (int q = 0; q < 8; ++q)
                            ga[c * 8 + q] += bf2f((unsigned short)hh[q])
                                           + bf2f((unsigned short)hl[q]);
                    }
                }
            }
            #pragma unroll
            for (int c = 0; c < 4; ++c) {
                const int kg = j4 * 4 + c;
                short8 hi, lo;
                #pragma unroll
                for (int q = 0; q < 8; ++q) {
                    float rem;
                    hi[q] = (short)bf_hi(ga[c * 8 + q], rem);
                    lo[q] = (short)f2bf(rem);
                }
                const int u = ((kg << 10) + row * 8) ^ (kg << 3);
                *(short8*)(Sf + u) = hi;
                *(short8*)(Sf + u + 16384) = lo;
            }
        }
        __syncthreads();
        {
            const unsigned short* __restrict__ B = wbL + (size_t)t * 32768;
            #pragma unroll
            for (int q = 0; q < 4; ++q) {
                const int kg = q * 4 + lkg;
                short8 ah[4], al[4];
                #pragma unroll
                for (int m = 0; m < 4; ++m) {
                    const int u = ((kg << 10) + (wr * 64 + m * 16 + lrow) * 8) ^ (kg << 3);
                    ah[m] = *(const short8*)(Sf + u);
                    al[m] = *(const short8*)(Sf + u + 16384);
                }
                #pragma unroll
                for (int n = 0; n < 4; ++n) {
                    const int ub = kg * 1024 + (wc * 64 + n * 16 + lrow) * 8;
                    const short8 bh = *(const short8*)(B + ub);
                    const short8 bl = *(const short8*)(B + ub + 16384);
                    #pragma unroll
                    for (int m = 0; m < 4; ++m) {
                        acc[m][n] = __builtin_amdgcn_mfma_f32_16x16x32_bf16(ah[m], bh, acc[m][n], 0, 0, 0);
                        acc[m][n] = __builtin_amdgcn_mfma_f32_16x16x32_bf16(ah[m], bl, acc[m][n], 0, 0, 0);
                        acc[m][n] = __builtin_amdgcn_mfma_f32_16x16x32_bf16(al[m], bh, acc[m][n], 0, 0, 0);
                    }
                }
            }
        }
        __syncthreads();
    }

    #pragma unroll
    for (int m = 0; m < 4; ++m)
        #pragma unroll
        for (int n = 0; n < 4; ++n) {
            const int col = wc * 64 + n * 16 + lrow;
            #pragma unroll
            for (int i = 0; i < 4; ++i) {
                const size_t Rg = (size_t)p * 128 + wr * 64 + m * 16 + lkg * 4 + i;
                agg[Rg * 128 + col] = acc[m][n][i];
            }
        }
}

// ---------------------------------------------------------------------------
// Fused GRU kernel (zr2+g2): per 128-row panel, everything panel-local.
// Phase 1 (pipelined, 8 quarter-stages): accZ = agg@k0 + h@rk0,
//   accR = agg@k1 + h@rk1, accG = agg@k2.
// Phase 2: z=sigmoid(accZ+bz) (kept), h read from global (kept in accR),
//   rh = sigmoid(accR+br)*h written split into full 64KB LDS panel.
// Phase 3: accG += rh@rk2 (4 quarters from LDS).
// Epilogue: h' = z*h + (1-z)*tanh(accG+bg) -> hP in place (own panel only).
// ---------------------------------------------------------------------------
__global__ __launch_bounds__(256) void zrg_kernel(
    const float* __restrict__ aggf, const unsigned short* __restrict__ hPc,
    const unsigned short* __restrict__ k0, const unsigned short* __restrict__ k1,
    const unsigned short* __restrict__ k2,
    const unsigned short* __restrict__ rk0, const unsigned short* __restrict__ rk1,
    const unsigned short* __restrict__ rk2,
    const float* __restrict__ bias,
    unsigned short* __restrict__ hP)
{
    __shared__ unsigned short lds[32768];   // 64KB: ph1 dbuf 2x16KB; ph3 full panel
    const int tid = threadIdx.x, p = blockIdx.x;
    const int wave = tid >> 6, lane = tid & 63;
    const int wr = wave >> 1, wc = wave & 1, lrow = lane & 15, lkg = lane >> 4;
    f32x4 accZ[4][4] = {}, accR[4][4] = {}, accG[4][4] = {};
    float fv[16];
    short8 ph[2], pl[2];

    auto ldq = [&](int s) {
        const int q = s & 3;
        #pragma unroll
        for (int j = 0; j < 2; ++j) {
            const int cid = j * 256 + tid, kgl = cid >> 7, row = cid & 127;
            if (s < 4) {
                const float* a = aggf + ((size_t)p * 128 + row) * 128 + q * 32 + kgl * 8;
                const float4 v0 = *(const float4*)(a);
                const float4 v1 = *(const float4*)(a + 4);
                fv[j*8+0]=v0.x; fv[j*8+1]=v0.y; fv[j*8+2]=v0.z; fv[j*8+3]=v0.w;
                fv[j*8+4]=v1.x; fv[j*8+5]=v1.y; fv[j*8+6]=v1.z; fv[j*8+7]=v1.w;
            } else {
                const unsigned short* hp = hPc + ((size_t)p * 128 + row) * 256 + (q * 4 + kgl) * 16;
                ph[j] = *(const short8*)(hp);
                pl[j] = *(const short8*)(hp + 8);
            }
        }
    };
    auto stq = [&](int buf, int s) {
        unsigned short* L = lds + buf * 8192;
        #pragma unroll
        for (int j = 0; j < 2; ++j) {
            const int cid = j * 256 + tid, kgl = cid >> 7, row = cid & 127;
            const int u = (kgl * 1024 + row * 8) ^ (kgl << 3);
            short8 hi, lo;
            if (s < 4) {
                #pragma unroll
                for (int q8 = 0; q8 < 8; ++q8) {
                    float rem; hi[q8] = (short)bf_hi(fv[j*8+q8], rem); lo[q8] = (short)f2bf(rem);
                }
            } else { hi = ph[j]; lo = pl[j]; }
            *(short8*)(L + u) = hi;
            *(short8*)(L + u + 4096) = lo;
        }
    };
    auto mfma_q = [&](int buf, int s) {
        const unsigned short* L = lds + buf * 8192;
        const int q = s & 3;
        short8 ah[4], al[4];
        #pragma unroll
        for (int m = 0; m < 4; ++m) {
            const int u = ((lkg << 10) + (wr * 64 + m * 16 + lrow) * 8) ^ (lkg << 3);
            ah[m] = *(const short8*)(L + u);
            al[m] = *(const short8*)(L + u + 4096);
        }
        const unsigned short* B0 = (s < 4) ? k0 : rk0;
        const unsigned short* B1 = (s < 4) ? k1 : rk1;
        #pragma unroll
        for (int n = 0; n < 4; ++n) {
            const int ub = (q * 4 + lkg) * 1024 + (wc * 64 + n * 16 + lrow) * 8;
            {
                const short8 bh = *(const short8*)(B0 + ub);
                const short8 bl = *(const short8*)(B0 + ub + 16384);
                #pragma unroll
                for (int m = 0; m < 4; ++m) {
                    accZ[m][n] = __builtin_amdgcn_mfma_f32_16x16x32_bf16(ah[m], bh, accZ[m][n], 0, 0, 0);
                    accZ[m][n] = __builtin_amdgcn_mfma_f32_16x16x32_bf16(ah[m], bl, accZ[m][n], 0, 0, 0);
                    accZ[m][n] = __builtin_amdgcn_mfma_f32_16x16x32_bf16(al[m], bh, accZ[m][n], 0, 0, 0);
                }
            }
            {
                const short8 bh = *(const short8*)(B1 + ub);
                const short8 bl = *(const short8*)(B1 + ub + 16384);
                #pragma unroll
                for (int m = 0; m < 4; ++m) {
                    accR[m][n] = __builtin_amdgcn_mfma_f32_16x16x32_bf16(ah[m], bh, accR[m][n], 0, 0, 0);
                    accR[m][n] = __builtin_amdgcn_mfma_f32_16x16x32_bf16(ah[m], bl, accR[m][n], 0, 0, 0);
                    accR[m][n] = __builtin_amdgcn_mfma_f32_16x16x32_bf16(al[m], bh, accR[m][n], 0, 0, 0);
                }
            }
            if (s < 4) {
                const short8 bh = *(const short8*)(k2 + ub);
                const short8 bl = *(const short8*)(k2 + ub + 16384);
                #pragma unroll
                for (int m = 0; m < 4; ++m) {
                    accG[m][n] = __builtin_amdgcn_mfma_f32_16x16x32_bf16(ah[m], bh, accG[m][n], 0, 0, 0);
                    accG[m][n] = __builtin_amdgcn_mfma_f32_16x16x32_bf16(ah[m], bl, accG[m][n], 0, 0, 0);
                    accG[m][n] = __builtin_amdgcn_mfma_f32_16x16x32_bf16(al[m], bh, accG[m][n], 0, 0, 0);
                }
            }
        }
    };

    ldq(0); stq(0, 0); ldq(1);
    __syncthreads();
    #pragma unroll
    for (int s = 0; s < 8; ++s) {
        mfma_q(s & 1, s);
        if (s < 7) {
            stq((s + 1) & 1, s + 1);
            if (s < 6) ldq(s + 2);
            __syncthreads();
        }
    }

    // phase 2: z kept in accZ, h kept in accR, rh -> full-panel LDS split
    __syncthreads();
    #pragma unroll
    for (int m = 0; m < 4; ++m)
        #pragma unroll
        for (int n = 0; n < 4; ++n) {
            const int col = wc * 64 + n * 16 + lrow;
            const int kg = col >> 3;
            #pragma unroll
            for (int i = 0; i < 4; ++i) {
                const int rl = wr * 64 + m * 16 + lkg * 4 + i;
                const size_t R = (size_t)p * 128 + rl;
                const float z = 1.f / (1.f + __expf(-(accZ[m][n][i] + bias[col])));
                const float r = 1.f / (1.f + __expf(-(accR[m][n][i] + bias[128 + col])));
                const size_t hu = R * 256 + (size_t)kg * 16 + (col & 7);
                const float h = bf2f(hPc[hu]) + bf2f(hPc[hu + 8]);
                accZ[m][n][i] = z;
                accR[m][n][i] = h;
                const float rh = r * h;
                float rem;
                const int u = ((kg << 10) + rl * 8 + (col & 7)) ^ (kg << 3);
                lds[u] = bf_hi(rh, rem);
                lds[u + 16384] = f2bf(rem);
            }
        }
    __syncthreads();

    // phase 3: accG += rh @ rk2
    #pragma unroll
    for (int q = 0; q < 4; ++q) {
        const int kg = q * 4 + lkg;
        short8 ah[4], al[4];
        #pragma unroll
        for (int m = 0; m < 4; ++m) {
            const int u = ((kg << 10) + (wr * 64 + m * 16 + lrow) * 8) ^ (kg << 3);
            ah[m] = *(const short8*)(lds + u);
            al[m] = *(const short8*)(lds + u + 16384);
        }
        #pragma unroll
        for (int n = 0; n < 4; ++n) {
            const int ub = kg * 1024 + (wc * 64 + n * 16 + lrow) * 8;
            const short8 bh = *(const short8*)(rk2 + ub);
            const short8 bl = *(const short8*)(rk2 + ub + 16384);
            #pragma unroll
            for (int m = 0; m < 4; ++m) {
                accG[m][n] = __builtin_amdgcn_mfma_f32_16x16x32_bf16(ah[m], bh, accG[m][n], 0, 0, 0);
                accG[m][n] = __builtin_amdgcn_mfma_f32_16x16x32_bf16(ah[m], bl, accG[m][n], 0, 0, 0);
                accG[m][n] = __builtin_amdgcn_mfma_f32_16x16x32_bf16(al[m], bh, accG[m][n], 0, 0, 0);
            }
        }
    }

    // epilogue: h' = z*h + (1-z)*tanh(G), split -> hP in place
    #pragma unroll
    for (int m = 0; m < 4; ++m)
        #pragma unroll
        for (int n = 0; n < 4; ++n) {
            const int col = wc * 64 + n * 16 + lrow;
            #pragma unroll
            for (int i = 0; i < 4; ++i) {
                const int rl = wr * 64 + m * 16 + lkg * 4 + i;
                const size_t R = (size_t)p * 128 + rl;
                const float g = accG[m][n][i] + bias[256 + col];
                const float z = accZ[m][n][i];
                const float h = accR[m][n][i];
                const float hn = z * h + (1.f - z) * tanhf(g);
                const size_t hu = R * 256 + (size_t)(col >> 3) * 16 + (col & 7);
                float rem; const unsigned short hh = bf_hi(hn, rem);
                hP[hu] = hh;
                hP[hu + 8] = f2bf(rem);
            }
        }
}

// ---------------------------------------------------------------------------
// V1 = leaky(h @ w1 + b1) -> f32
// ---------------------------------------------------------------------------
__global__ __launch_bounds__(256) void v1_kernel(
    const unsigned short* __restrict__ hP, const unsigned short* __restrict__ w1b,
    const float* __restrict__ bias, float* __restrict__ outF)
{
    __shared__ unsigned short lds[2][8192];
    const int tid = threadIdx.x, p = blockIdx.x;
    const int wave = tid >> 6, lane = tid & 63;
    const int wr = wave >> 1, wc = wave & 1, lrow = lane & 15, lkg = lane >> 4;
    f32x4 acc[4][4] = {};
    short8 ph[2], pl[2];

    auto ldq = [&](int s) {
        #pragma unroll
        for (int j = 0; j < 2; ++j) {
            const int cid = j * 256 + tid, kgl = cid >> 7, row = cid & 127;
            const unsigned short* hp = hP + ((size_t)p * 128 + row) * 256 + (s * 4 + kgl) * 16;
            ph[j] = *(const short8*)(hp);
            pl[j] = *(const short8*)(hp + 8);
        }
    };
    auto stq = [&](int buf) {
        unsigned short* L = lds[buf];
        #pragma unroll
        for (int j = 0; j < 2; ++j) {
            const int cid = j * 256 + tid, kgl = cid >> 7, row = cid & 127;
            const int u = (kgl * 1024 + row * 8) ^ (kgl << 3);
            *(short8*)(L + u) = ph[j];
            *(short8*)(L + u + 4096) = pl[j];
        }
    };
    auto mfma_q = [&](int buf, int s) {
        const unsigned short* L = lds[buf];
        short8 ah[4], al[4];
        #pragma unroll
        for (int m = 0; m < 4; ++m) {
            const int u = ((lkg << 10) + (wr * 64 + m * 16 + lrow) * 8) ^ (lkg << 3);
            ah[m] = *(const short8*)(L + u);
            al[m] = *(const short8*)(L + u + 4096);
        }
        #pragma unroll
        for (int n = 0; n < 4; ++n) {
            const int ub = (s * 4 + lkg) * 1024 + (wc * 64 + n * 16 + lrow) * 8;
            const short8 bh = *(const short8*)(w1b + ub);
            const short8 bl = *(const short8*)(w1b + ub + 16384);
            #pragma unroll
            for (int m = 0; m < 4; ++m) {
                acc[m][n] = __builtin_amdgcn_mfma_f32_16x16x32_bf16(ah[m], bh, acc[m][n], 0, 0, 0);
                acc[m][n] = __builtin_amdgcn_mfma_f32_16x16x32_bf16(ah[m], bl, acc[m][n], 0, 0, 0);
                acc[m][n] = __builtin_amdgcn_mfma_f32_16x16x32_bf16(al[m], bh, acc[m][n], 0, 0, 0);
            }
        }
    };

    ldq(0); stq(0); ldq(1);
    __syncthreads();
    #pragma unroll
    for (int s = 0; s < 4; ++s) {
        mfma_q(s & 1, s);
        if (s < 3) {
            stq((s + 1) & 1);
            if (s < 2) ldq(s + 2);
            __syncthreads();
        }
    }

    #pragma unroll
    for (int m = 0; m < 4; ++m)
        #pragma unroll
        for (int n = 0; n < 4; ++n) {
            const int col = wc * 64 + n * 16 + lrow;
            #pragma unroll
            for (int i = 0; i < 4; ++i) {
                const size_t R = (size_t)p * 128 + wr * 64 + m * 16 + lkg * 4 + i;
                float v = acc[m][n][i] + bias[col];
                v = v > 0.f ? v : LEAKY_SLOPE * v;
                outF[R * 128 + col] = v;
            }
        }
}

// ---------------------------------------------------------------------------
// Final: thread-per-node; wave-uniform graph atomic (n2g sorted).
// ---------------------------------------------------------------------------
__global__ __launch_bounds__(256) void final_kernel(
    const unsigned short* __restrict__ hP, const float* __restrict__ V1,
    const int* __restrict__ n2g,
    const float* __restrict__ w2, const float* __restrict__ b2,
    const float* __restrict__ w3, const float* __restrict__ b3,
    const float* __restrict__ w4, const float* __restrict__ b4,
    const float* __restrict__ score_w, const float* __restrict__ score_b,
    float* __restrict__ out, int N)
{
    const int n = blockIdx.x * blockDim.x + threadIdx.x;
    const int nc = n < N ? n : N - 1;
    const int g = n2g[nc];

    float sp = score_b[0];
    #pragma unroll 4
    for (int kg = 0; kg < 16; ++kg) {
        const size_t hu = (size_t)nc * 256 + kg * 16;
        const short8 hh = *(const short8*)(hP + hu);
        const short8 hl = *(const short8*)(hP + hu + 8);
        #pragma unroll
        for (int j = 0; j < 8; ++j)
            sp += (bf2f((unsigned short)hh[j]) + bf2f((unsigned short)hl[j])) * score_w[kg * 8 + j];
    }

    float V2[32];
    #pragma unroll
    for (int j = 0; j < 32; ++j) V2[j] = b2[j];
    #pragma unroll 2
    for (int k = 0; k < 128; k += 4) {
        const float4 v1 = *reinterpret_cast<const float4*>(V1 + (size_t)nc * 128 + k);
        const float vv[4] = {v1.x, v1.y, v1.z, v1.w};
        #pragma unroll
        for (int kk = 0; kk < 4; ++kk)
            #pragma unroll
            for (int j = 0; j < 32; ++j)
                V2[j] += vv[kk] * w2[(k + kk) * 32 + j];
    }
    #pragma unroll
    for (int j = 0; j < 32; ++j) { const float x = V2[j]; V2[j] = x > 0.f ? x : LEAKY_SLOPE * x; }

    float V3[8];
    #pragma unroll
    for (int j = 0; j < 8; ++j) V3[j] = b3[j];
    #pragma unroll
    for (int k = 0; k < 32; ++k)
        #pragma unroll
        for (int j = 0; j < 8; ++j) V3[j] += V2[k] * w3[k * 8 + j];
    #pragma unroll
    for (int j = 0; j < 8; ++j) { const float x = V3[j]; V3[j] = x > 0.f ? x : LEAKY_SLOPE * x; }

    float o4 = b4[0];
    #pragma unroll
    for (int j = 0; j < 8; ++j) o4 += V3[j] * w4[j];

    const float sc = 1.f / (1.f + __expf(-sp));
    float val = (n < N) ? sc * o4 : 0.f;

    const int g0 = __shfl(g, 0, 64);
    if (__all(g == g0)) {
        #pragma unroll
        for (int d = 32; d > 0; d >>= 1) val += __shfl_xor(val, d, 64);
        if ((threadIdx.x & 63) == 0) unsafeAtomicAdd(out + g0, val);
    } else {
        if (n < N) unsafeAtomicAdd(out + g, val);
    }
}

// ---------------------------------------------------------------------------
extern "C" void kernel_launch(void* const* d_in, const int* in_sizes, int n_in,
                              void* d_out, int out_size, void* d_ws, size_t ws_size,
                              hipStream_t stream)
{
    (void)n_in;
    const int* labels   = (const int*)d_in[1];
    const int* nidx     = (const int*)d_in[2];
    const int* n2g      = (const int*)d_in[3];
    EdgeArgs ea;
    int Emax = 0, Etot = 0;
    for (int t = 0; t < 12; ++t) {
        ea.adj[t] = (const int*)d_in[5 + t];
        ea.E[t] = in_sizes[5 + t] / 2;
        ea.colOff[t] = Etot;
        Etot += ea.E[t];
        if (ea.E[t] > Emax) Emax = ea.E[t];
    }
    const float* char_embed = (const float*)d_in[17];
    const float* conv_w     = (const float*)d_in[18];
    const float* conv_b     = (const float*)d_in[19];
    const float* W_msg      = (const float*)d_in[20];
    const float* gru_k      = (const float*)d_in[21];
    const float* gru_rk     = (const float*)d_in[22];
    const float* gru_b      = (const float*)d_in[23];
    const float* score_w    = (const float*)d_in[24];
    const float* score_b    = (const float*)d_in[25];
    const float* w1 = (const float*)d_in[26];
    const float* b1 = (const float*)d_in[27];
    const float* w2 = (const float*)d_in[28];
    const float* b2 = (const float*)d_in[29];
    const float* w3 = (const float*)d_in[30];
    const float* b3 = (const float*)d_in[31];
    const float* w4 = (const float*)d_in[32];
    const float* b4 = (const float*)d_in[33];

    const int N = in_sizes[2];
    const int U = in_sizes[1] / 16;
    const int G = out_size;
    float* out = (float*)d_out;

    const int NPB = cdiv(N, 128);
    const int NP  = NPB * 128;
    const int NCHUNK = cdiv(N, 2048);
    const int NMAT = 109;

    // ---- workspace (~165 MB) ----
    float* ws = (float*)d_ws;
    size_t o = 0;
    float* lr   = ws + o; o += (size_t)U * 64;
    float* hPf  = ws + o; o += (size_t)NP * 128;   // h packed-split (u16 hi/lo)
    float* aggf = ws + o; o += (size_t)NP * 128;   // agg f32 (CSR temps early; V1 late)
    float* wbf  = ws + o; o += (size_t)NMAT * 16384;
    int* rowptr = (int*)(ws + o);
    int* colarr = rowptr + (size_t)12 * (N + 1);
    const size_t total_bytes = o * sizeof(float)
        + ((size_t)12 * (N + 1) + (size_t)Etot) * sizeof(int);
    if (total_bytes > ws_size) return;

    unsigned short* hP = (unsigned short*)hPf;
    unsigned short* wb = (unsigned short*)wbf;

    // CSR temporaries inside aggf region (free until layer-0 agg writes it)
    int* deg     = (int*)aggf;
    int* cursor  = deg + (size_t)12 * N;
    int* partial = cursor + (size_t)12 * N;

    hipMemsetAsync(d_out, 0, (size_t)G * sizeof(float), stream);
    hipMemsetAsync(deg, 0, ((size_t)24 * N + 12 * NCHUNK) * sizeof(int), stream);

    MutColPtrs mcp;
    ColPtrs cps;
    for (int t = 0; t < 12; ++t) {
        mcp.c[t] = colarr + ea.colOff[t];
        cps.c[t] = colarr + ea.colOff[t];
    }

    {
        const dim3 ge(cdiv(Emax, 256), 12);
        const dim3 gs(NCHUNK, 12);
        const dim3 gn(cdiv(N, 256), 12);
        hist_kernel<<<ge, 256, 0, stream>>>(ea, deg, N);
        scan_a<<<gs, 256, 0, stream>>>(deg, partial, N, NCHUNK);
        scan_b<<<1, 64, 0, stream>>>(partial, NCHUNK);
        scan_c<<<gs, 256, 0, stream>>>(deg, partial, rowptr, N, NCHUNK);
        fill_kernel<<<ge, 256, 0, stream>>>(ea, rowptr, cursor, colarr, N);
        // Canonical order: makes every downstream fp32 reduction call-invariant.
        sort_cols_kernel<<<gn, 256, 0, stream>>>(rowptr, mcp, N);
    }

    WSrc wsrc{W_msg, gru_k, gru_rk, w1};
    split_w_kernel<<<cdiv(NMAT * 16384, 256), 256, 0, stream>>>(wsrc, wb, NMAT);
    label_kernel<<<U, 64, 0, stream>>>(labels, char_embed, conv_w, conv_b, lr, U);
    init_hP<<<cdiv(NP * 16, 256), 256, 0, stream>>>(nidx, lr, hP, N, NP);

    auto wbm = [&](int m) { return wb + (size_t)m * 32768; };

    for (int layer = 0; layer < 6; ++layer) {
        const float* bl = gru_b + (size_t)layer * 384;
        const int mk = 72 + layer * 6;
        agg_kernel<<<NPB, 256, 0, stream>>>(hP, rowptr, cps,
                                            wbm(layer * 12), aggf, N);
        zrg_kernel<<<NPB, 256, 0, stream>>>(aggf, hP,
                                            wbm(mk + 0), wbm(mk + 1), wbm(mk + 2),
                                            wbm(mk + 3), wbm(mk + 4), wbm(mk + 5),
                                            bl, hP);
    }
    v1_kernel<<<NPB, 256, 0, stream>>>(hP, wbm(108), b1, aggf);
    final_kernel<<<cdiv(N, 256), 256, 0, stream>>>(hP, aggf, n2g, w2, b2, w3, b3, w4, b4,
                                                   score_w, score_b, out, N);
}